// Round 9
// baseline (112.471 us; speedup 1.0000x reference)
//
#include <hip/hip_runtime.h>

// Problem constants (from reference): B=32, L=4096, D=128, N=5, V=128
constexpr int Bn = 32;
constexpr int Ln = 4096;
constexpr int Dn = 128;
constexpr int Vn = 128;
constexpr int N1 = 4;  // N - 1 context slots

typedef float vfloat4 __attribute__((ext_vector_type(4)));  // native vec for nontemporal builtins

// R15 = R14 (pair-sum tables + ws_size guard), third submission.
// R7/R8 benches died with "container failed twice"; guard analysis + the R4
// failure (a kernel with NO ws writes) says the failures are time-clustered
// infra, not content. Pair theory unchanged: five gather/store/depth variants
// (R0-R3, R6) all pinned at 92+-1.5us; the invariant is the 268 MB gather byte
// count (4 table floats per output float). Pair tables halve it:
//   P01[a*128+b][v] = T0[a][v]+T1[b][v]   (bias folded in T0)
//   P23[a*128+b][v] = T2[a][v]+T3[b][v]
//   out[j] = P01[x[j-4],x[j-3]] + P23[x[j-2],x[j-1]]  -> 2 gathers, 1 add.
// R15 cleanup: pair_build now 4096 blocks x one float4 NT store per thread
// (was 16384 blocks x scalar store).
//
// Kernel A (proven): T[k][t][v] = dot(emb[t], W[v,kD:(k+1)D]) (+bias for k==0).
__global__ void build_table_kernel(const float* __restrict__ emb,
                                   const float* __restrict__ W,
                                   const float* __restrict__ bias,
                                   float* __restrict__ T) {
    const int kt = blockIdx.x;        // k*128 + t
    const int k  = kt >> 7;
    const int t  = kt & 127;
    const int v  = threadIdx.x;       // 0..127

    __shared__ float4 e[Dn / 4];
    if (threadIdx.x < Dn / 4) {
        e[threadIdx.x] = ((const float4*)(emb + t * Dn))[threadIdx.x];
    }
    __syncthreads();

    const float4* w = (const float4*)(W + (size_t)v * (Dn * N1) + k * Dn);
    float acc = (k == 0) ? bias[v] : 0.f;  // fold bias into slot-0 table
#pragma unroll
    for (int i = 0; i < Dn / 4; ++i) {
        float4 wv = w[i];
        float4 ev = e[i];
        acc += wv.x * ev.x + wv.y * ev.y + wv.z * ev.z + wv.w * ev.w;
    }
    T[(size_t)kt * Vn + v] = acc;  // plain [4][128][128] layout
}

// Kernel P: expand T to pair tables (16 MiB, ~3us of NT writes).
// One float4 per thread: fid -> (half, ab, vq). Within a wave, 32 consecutive
// lanes share ab and sweep vq 0..31 -> Ta/Tb row reads are coalesced 512 B,
// P writes are contiguous 512 B rows. Reads hit the 256 KiB L2-resident T.
__global__ void __launch_bounds__(256, 8)
pair_build_kernel(const float* __restrict__ T, float* __restrict__ P) {
    const int fid  = blockIdx.x * 256 + threadIdx.x;  // float4 id, 0..1048575
    const int half = fid >> 19;                       // 0 -> P01, 1 -> P23
    const int rem  = fid & ((1 << 19) - 1);
    const int ab   = rem >> 5;                        // a*128 + b
    const int vq   = rem & 31;
    const int a    = ab >> 7;
    const int b    = ab & 127;

    const vfloat4* Ta = (const vfloat4*)(T + (size_t)((half * 2 + 0) * Vn + a) * Vn);
    const vfloat4* Tb = (const vfloat4*)(T + (size_t)((half * 2 + 1) * Vn + b) * Vn);
    const vfloat4  s  = Ta[vq] + Tb[vq];
    __builtin_nontemporal_store(s, (vfloat4*)P + (size_t)fid);
}

// Kernel B-pair: out[b,j,v] = P01[pair01(j)] + P23[pair23(j)].
// R6 structure: thread = 8 consecutive positions x one float4 of v, x-window
// preloaded, unrolled batches, full-row 512 B contiguous NT stores.
__global__ void __launch_bounds__(256, 4)
ngram_logits_pair_kernel(const int* __restrict__ x,
                         const float* __restrict__ P,
                         const float* __restrict__ bias,
                         float* __restrict__ out) {
    const int tid = blockIdx.x * 256 + threadIdx.x;
    const int vq  = tid & 31;          // float4 column within the full 128-v row
    const int G   = tid >> 5;          // 8-position group, 0..16383
    const int basepos = G << 3;        // 8-aligned
    const int j0      = basepos & (Ln - 1);

    const vfloat4* P01 = (const vfloat4*)P;                        // [16384][32]
    const vfloat4* P23 = (const vfloat4*)(P + (size_t)Vn * Vn * Vn);
    vfloat4*      outq = (vfloat4*)out;
    vfloat4*      ob   = outq + (size_t)basepos * 32 + vq;

    // token window w[0..10] = x[basepos-4 .. basepos+6]
    int w[11];
    const int4 xb = *(const int4*)(x + basepos);
    const int4 xc = *(const int4*)(x + basepos + 4);
    w[4] = xb.x; w[5] = xb.y; w[6] = xb.z; w[7] = xb.w;
    w[8] = xc.x; w[9] = xc.y; w[10] = xc.z;

    if (j0 == 0) {
        // positions 0..3 of a batch row: bias-only rows
        const vfloat4 bv = ((const vfloat4*)bias)[vq];
#pragma unroll
        for (int i = 0; i < 4; ++i)
            __builtin_nontemporal_store(bv, ob + i * 32);
    } else {
        const int4 xa = *(const int4*)(x + basepos - 4);
        w[0] = xa.x; w[1] = xa.y; w[2] = xa.z; w[3] = xa.w;
        vfloat4 a0 = P01[(size_t)((w[0] << 7) + w[1]) * 32 + vq];
        vfloat4 a1 = P01[(size_t)((w[1] << 7) + w[2]) * 32 + vq];
        vfloat4 a2 = P01[(size_t)((w[2] << 7) + w[3]) * 32 + vq];
        vfloat4 a3 = P01[(size_t)((w[3] << 7) + w[4]) * 32 + vq];
        a0 += P23[(size_t)((w[2] << 7) + w[3]) * 32 + vq];
        a1 += P23[(size_t)((w[3] << 7) + w[4]) * 32 + vq];
        a2 += P23[(size_t)((w[4] << 7) + w[5]) * 32 + vq];
        a3 += P23[(size_t)((w[5] << 7) + w[6]) * 32 + vq];
        __builtin_nontemporal_store(a0, ob + 0 * 32);
        __builtin_nontemporal_store(a1, ob + 1 * 32);
        __builtin_nontemporal_store(a2, ob + 2 * 32);
        __builtin_nontemporal_store(a3, ob + 3 * 32);
    }

    {   // batch 1: positions 4..7 (window entirely within this batch row)
        vfloat4 a0 = P01[(size_t)((w[4] << 7) + w[5]) * 32 + vq];
        vfloat4 a1 = P01[(size_t)((w[5] << 7) + w[6]) * 32 + vq];
        vfloat4 a2 = P01[(size_t)((w[6] << 7) + w[7]) * 32 + vq];
        vfloat4 a3 = P01[(size_t)((w[7] << 7) + w[8]) * 32 + vq];
        a0 += P23[(size_t)((w[6] << 7) + w[7]) * 32 + vq];
        a1 += P23[(size_t)((w[7] << 7) + w[8]) * 32 + vq];
        a2 += P23[(size_t)((w[8] << 7) + w[9]) * 32 + vq];
        a3 += P23[(size_t)((w[9] << 7) + w[10]) * 32 + vq];
        __builtin_nontemporal_store(a0, ob + 4 * 32);
        __builtin_nontemporal_store(a1, ob + 5 * 32);
        __builtin_nontemporal_store(a2, ob + 6 * 32);
        __builtin_nontemporal_store(a3, ob + 7 * 32);
    }
}

// Kernel B-direct: the proven R6 4-gather path (fallback when ws is small).
__global__ void __launch_bounds__(256, 4)
ngram_logits_direct_kernel(const int* __restrict__ x,
                           const float* __restrict__ T,
                           const float* __restrict__ bias,
                           float* __restrict__ out) {
    const int tid = blockIdx.x * 256 + threadIdx.x;
    const int vq  = tid & 31;
    const int G   = tid >> 5;
    const int basepos = G << 3;
    const int j0      = basepos & (Ln - 1);

    const vfloat4* Tq   = (const vfloat4*)T;  // [512 rows][32 float4]
    vfloat4*       outq = (vfloat4*)out;
    vfloat4*       ob   = outq + (size_t)basepos * 32 + vq;

    int w[11];
    const int4 xb = *(const int4*)(x + basepos);
    const int4 xc = *(const int4*)(x + basepos + 4);
    w[4] = xb.x; w[5] = xb.y; w[6] = xb.z; w[7] = xb.w;
    w[8] = xc.x; w[9] = xc.y; w[10] = xc.z;

    if (j0 == 0) {
        const vfloat4 bv = ((const vfloat4*)bias)[vq];
#pragma unroll
        for (int i = 0; i < 4; ++i)
            __builtin_nontemporal_store(bv, ob + i * 32);
    } else {
        const int4 xa = *(const int4*)(x + basepos - 4);
        w[0] = xa.x; w[1] = xa.y; w[2] = xa.z; w[3] = xa.w;
        vfloat4 a0 = Tq[(size_t)(0 * Vn + w[0]) * 32 + vq];
        vfloat4 a1 = Tq[(size_t)(0 * Vn + w[1]) * 32 + vq];
        vfloat4 a2 = Tq[(size_t)(0 * Vn + w[2]) * 32 + vq];
        vfloat4 a3 = Tq[(size_t)(0 * Vn + w[3]) * 32 + vq];
#pragma unroll
        for (int k = 1; k < N1; ++k) {
            a0 += Tq[(size_t)(k * Vn + w[0 + k]) * 32 + vq];
            a1 += Tq[(size_t)(k * Vn + w[1 + k]) * 32 + vq];
            a2 += Tq[(size_t)(k * Vn + w[2 + k]) * 32 + vq];
            a3 += Tq[(size_t)(k * Vn + w[3 + k]) * 32 + vq];
        }
        __builtin_nontemporal_store(a0, ob + 0 * 32);
        __builtin_nontemporal_store(a1, ob + 1 * 32);
        __builtin_nontemporal_store(a2, ob + 2 * 32);
        __builtin_nontemporal_store(a3, ob + 3 * 32);
    }

    {
        vfloat4 a0 = Tq[(size_t)(0 * Vn + w[4]) * 32 + vq];
        vfloat4 a1 = Tq[(size_t)(0 * Vn + w[5]) * 32 + vq];
        vfloat4 a2 = Tq[(size_t)(0 * Vn + w[6]) * 32 + vq];
        vfloat4 a3 = Tq[(size_t)(0 * Vn + w[7]) * 32 + vq];
#pragma unroll
        for (int k = 1; k < N1; ++k) {
            a0 += Tq[(size_t)(k * Vn + w[4 + k]) * 32 + vq];
            a1 += Tq[(size_t)(k * Vn + w[5 + k]) * 32 + vq];
            a2 += Tq[(size_t)(k * Vn + w[6 + k]) * 32 + vq];
            a3 += Tq[(size_t)(k * Vn + w[7 + k]) * 32 + vq];
        }
        __builtin_nontemporal_store(a0, ob + 4 * 32);
        __builtin_nontemporal_store(a1, ob + 5 * 32);
        __builtin_nontemporal_store(a2, ob + 6 * 32);
        __builtin_nontemporal_store(a3, ob + 7 * 32);
    }
}

extern "C" void kernel_launch(void* const* d_in, const int* in_sizes, int n_in,
                              void* d_out, int out_size, void* d_ws, size_t ws_size,
                              hipStream_t stream) {
    const int*   x    = (const int*)d_in[0];    // (B, L) int32
    const float* emb  = (const float*)d_in[1];  // (V, D) fp32
    const float* W    = (const float*)d_in[2];  // (V, D*(N-1)) fp32
    const float* bias = (const float*)d_in[3];  // (V,) fp32
    float*       out  = (float*)d_out;          // (B, L, V) fp32

    float* T = (float*)d_ws;                    // [4][128][128] = 256 KiB
    build_table_kernel<<<N1 * Vn, Vn, 0, stream>>>(emb, W, bias, T);

    // Pair tables need 256 KiB (T) + 16 MiB (P). Guard on the REAL ws_size;
    // host-side branch on a capture-time constant is graph-capture-safe.
    const size_t need = (size_t)(N1 * Vn * Vn) * 4 + (size_t)2 * Vn * Vn * Vn * 4;
    if (ws_size >= need) {
        float* P = T + (size_t)N1 * Vn * Vn;    // [2][16384][128]
        pair_build_kernel<<<4096, 256, 0, stream>>>(T, P);
        ngram_logits_pair_kernel<<<2048, 256, 0, stream>>>(x, P, bias, out);
    } else {
        // Proven R6 fallback (ws too small for pair tables)
        ngram_logits_direct_kernel<<<2048, 256, 0, stream>>>(x, T, bias, out);
    }
}

// Round 10
// 91.695 us; speedup vs baseline: 1.2266x; 1.2266x over previous
//
#include <hip/hip_runtime.h>

// Problem constants (from reference): B=32, L=4096, D=128, N=5, V=128
constexpr int Bn = 32;
constexpr int Ln = 4096;
constexpr int Dn = 128;
constexpr int Vn = 128;
constexpr int N1 = 4;  // N - 1 context slots

typedef float vfloat4 __attribute__((ext_vector_type(4)));  // native vec for nontemporal builtins

// R16: FINAL — revert to the proven R6 two-kernel direct form.
// Session ledger (10 rounds):
//  - gather mechanism: L2-direct / LDS-eighth / LDS-quarter / LDS-swizzled all
//    NEUTRAL (92 +- 1.5us) -> gather path never on the critical path.
//  - store shape: the ONLY real lever. Full-row 512 B contiguous NT stores
//    required; 64 B chunked stores cost +8us (R1). NT required (prior session).
//  - MLP depth: 8 pos/thread, 16 gathers in flight — neutral (R6).
//  - gather bytes: pair-sum tables (2 gathers instead of 4, 16 MiB tables)
//    REGRESSED ~+10-20us — tables spill the 4 MiB XCD L2 into L3 latency (R9).
//  - fusion (per-block table build in LDS): catastrophic, 128x W re-read (R5).
// Timed-region decomposition: ~57us harness poison fills (268 MB ws + 67 MB out
// at ~5.9 TB/s, outside our control) + ~5us build + ~25us ngram + gaps ~= 92us.
// ngram's own floor (64 MiB NT stores + gathers) ~= 12-15us; five structural
// rewrites could not extract the residual ~10us of dependent-chain latency.
// This is the practical floor for this harness.
//
// Kernel A: T[k][t][v] = dot(emb[t], W[v, k*D:(k+1)*D]) (+ bias[v] for k==0).
__global__ void build_table_kernel(const float* __restrict__ emb,
                                   const float* __restrict__ W,
                                   const float* __restrict__ bias,
                                   float* __restrict__ T) {
    const int kt = blockIdx.x;        // k*128 + t
    const int k  = kt >> 7;
    const int t  = kt & 127;
    const int v  = threadIdx.x;       // 0..127

    __shared__ float4 e[Dn / 4];
    if (threadIdx.x < Dn / 4) {
        e[threadIdx.x] = ((const float4*)(emb + t * Dn))[threadIdx.x];
    }
    __syncthreads();

    const float4* w = (const float4*)(W + (size_t)v * (Dn * N1) + k * Dn);
    float acc = (k == 0) ? bias[v] : 0.f;  // fold bias into slot-0 table
#pragma unroll
    for (int i = 0; i < Dn / 4; ++i) {
        float4 wv = w[i];
        float4 ev = e[i];
        acc += wv.x * ev.x + wv.y * ev.y + wv.z * ev.z + wv.w * ev.w;
    }
    T[(size_t)kt * Vn + v] = acc;  // plain [4][128][128] layout
}

// Kernel B: out[b,j,v] = sum_k T[k][x[b,j-4+k]][v], bias folded into T[0].
// Thread = 8 consecutive positions x one float4 of v. Wave = 2 groups x 32 vq
// lanes -> every gather instruction reads a contiguous 512 B table row and every
// NT-store instruction writes 2 x 512 B contiguous (the proven store shape).
// x-window preloaded; two fully-unrolled 16-gather batches per thread.
__global__ void __launch_bounds__(256, 4)
ngram_logits_kernel(const int* __restrict__ x,
                    const float* __restrict__ T,
                    const float* __restrict__ bias,
                    float* __restrict__ out) {
    const int tid = blockIdx.x * 256 + threadIdx.x;
    const int vq  = tid & 31;          // float4 column within the full 128-v row
    const int G   = tid >> 5;          // 8-position group, 0..16383
    const int basepos = G << 3;        // 8-aligned
    const int j0      = basepos & (Ln - 1);

    const vfloat4* Tq   = (const vfloat4*)T;  // [512 rows][32 float4]
    vfloat4*       outq = (vfloat4*)out;
    vfloat4*       ob   = outq + (size_t)basepos * 32 + vq;

    // token window w[0..10] = x[basepos-4 .. basepos+6]
    int w[11];
    const int4 xb = *(const int4*)(x + basepos);
    const int4 xc = *(const int4*)(x + basepos + 4);
    w[4] = xb.x; w[5] = xb.y; w[6] = xb.z; w[7] = xb.w;
    w[8] = xc.x; w[9] = xc.y; w[10] = xc.z;

    if (j0 == 0) {
        // positions 0..3 of a batch row: bias-only rows (w[0..3] unused)
        const vfloat4 bv = ((const vfloat4*)bias)[vq];
#pragma unroll
        for (int i = 0; i < 4; ++i)
            __builtin_nontemporal_store(bv, ob + i * 32);
    } else {
        const int4 xa = *(const int4*)(x + basepos - 4);
        w[0] = xa.x; w[1] = xa.y; w[2] = xa.z; w[3] = xa.w;
        // batch 0: positions 0..3 — 16 independent gathers, then 4 NT stores
        vfloat4 a0 = Tq[(size_t)(0 * Vn + w[0]) * 32 + vq];
        vfloat4 a1 = Tq[(size_t)(0 * Vn + w[1]) * 32 + vq];
        vfloat4 a2 = Tq[(size_t)(0 * Vn + w[2]) * 32 + vq];
        vfloat4 a3 = Tq[(size_t)(0 * Vn + w[3]) * 32 + vq];
#pragma unroll
        for (int k = 1; k < N1; ++k) {
            a0 += Tq[(size_t)(k * Vn + w[0 + k]) * 32 + vq];
            a1 += Tq[(size_t)(k * Vn + w[1 + k]) * 32 + vq];
            a2 += Tq[(size_t)(k * Vn + w[2 + k]) * 32 + vq];
            a3 += Tq[(size_t)(k * Vn + w[3 + k]) * 32 + vq];
        }
        __builtin_nontemporal_store(a0, ob + 0 * 32);
        __builtin_nontemporal_store(a1, ob + 1 * 32);
        __builtin_nontemporal_store(a2, ob + 2 * 32);
        __builtin_nontemporal_store(a3, ob + 3 * 32);
    }

    // batch 1: positions 4..7 (window entirely within this batch row)
    {
        vfloat4 a0 = Tq[(size_t)(0 * Vn + w[4]) * 32 + vq];
        vfloat4 a1 = Tq[(size_t)(0 * Vn + w[5]) * 32 + vq];
        vfloat4 a2 = Tq[(size_t)(0 * Vn + w[6]) * 32 + vq];
        vfloat4 a3 = Tq[(size_t)(0 * Vn + w[7]) * 32 + vq];
#pragma unroll
        for (int k = 1; k < N1; ++k) {
            a0 += Tq[(size_t)(k * Vn + w[4 + k]) * 32 + vq];
            a1 += Tq[(size_t)(k * Vn + w[5 + k]) * 32 + vq];
            a2 += Tq[(size_t)(k * Vn + w[6 + k]) * 32 + vq];
            a3 += Tq[(size_t)(k * Vn + w[7 + k]) * 32 + vq];
        }
        __builtin_nontemporal_store(a0, ob + 4 * 32);
        __builtin_nontemporal_store(a1, ob + 5 * 32);
        __builtin_nontemporal_store(a2, ob + 6 * 32);
        __builtin_nontemporal_store(a3, ob + 7 * 32);
    }
}

extern "C" void kernel_launch(void* const* d_in, const int* in_sizes, int n_in,
                              void* d_out, int out_size, void* d_ws, size_t ws_size,
                              hipStream_t stream) {
    const int*   x    = (const int*)d_in[0];    // (B, L) int32
    const float* emb  = (const float*)d_in[1];  // (V, D) fp32
    const float* W    = (const float*)d_in[2];  // (V, D*(N-1)) fp32
    const float* bias = (const float*)d_in[3];  // (V,) fp32
    float*       out  = (float*)d_out;          // (B, L, V) fp32
    float*       T    = (float*)d_ws;           // (4, 128, 128) fp32 = 256 KiB

    build_table_kernel<<<N1 * Vn, Vn, 0, stream>>>(emb, W, bias, T);

    // 16384 position-groups x 32 v-columns / 256 threads = 2048 blocks
    ngram_logits_kernel<<<2048, 256, 0, stream>>>(x, T, bias, out);
}